// Round 1
// baseline (1130.805 us; speedup 1.0000x reference)
//
#include <hip/hip_runtime.h>
#include <hip/hip_bf16.h>

// ---------------- problem constants ----------------
#define DIMD 384
#define HEADS 6
#define DH 64
#define LEVELS 3
#define POINTS 4
#define FFN 1024
#define BB 4
#define NQ 4096
#define NV 21504
#define MQ (BB*NQ)   // 16384
#define MV (BB*NV)   // 86016
#define EPSF 1e-6f

typedef __hip_bfloat16 bf16;

__device__ __forceinline__ float wave_sum(float v){
  #pragma unroll
  for(int o=32;o;o>>=1) v += __shfl_xor(v,o);
  return v;
}

// ---------------- per-row mean/rstd (for LN fused into GEMM A-load) ----------------
__global__ __launch_bounds__(256) void row_stats_k(const float* __restrict__ x,
                                                   float* __restrict__ stats, int nrows){
  int row = blockIdx.x*4 + (threadIdx.x>>6);
  int lane = threadIdx.x & 63;
  if(row >= nrows) return;
  const float* xr = x + (size_t)row*DIMD;
  float s=0.f, s2=0.f;
  #pragma unroll
  for(int i=0;i<DIMD/64;i++){ float v = xr[lane + i*64]; s += v; s2 += v*v; }
  s = wave_sum(s); s2 = wave_sum(s2);
  float m = s*(1.f/DIMD);
  float var = s2*(1.f/DIMD) - m*m;
  float r = rsqrtf(var + EPSF);
  if(lane==0){ stats[2*row]=m; stats[2*row+1]=r; }
}

// ---------------- row LayerNorm; FINAL=1 additionally does out = q + gamma*t ----------------
template<int FINAL>
__global__ __launch_bounds__(256) void row_ln_k(const float* __restrict__ x,
    const float* __restrict__ g, const float* __restrict__ b,
    const float* __restrict__ q, const float* __restrict__ gamma,
    float* __restrict__ out, int nrows){
  int row = blockIdx.x*4 + (threadIdx.x>>6);
  int lane = threadIdx.x & 63;
  if(row >= nrows) return;
  const float* xr = x + (size_t)row*DIMD;
  float vals[DIMD/64];
  float s=0.f, s2=0.f;
  #pragma unroll
  for(int i=0;i<DIMD/64;i++){ float v = xr[lane + i*64]; vals[i]=v; s += v; s2 += v*v; }
  s = wave_sum(s); s2 = wave_sum(s2);
  float m = s*(1.f/DIMD);
  float var = s2*(1.f/DIMD) - m*m;
  float r = rsqrtf(var + EPSF);
  #pragma unroll
  for(int i=0;i<DIMD/64;i++){
    int k = lane + i*64;
    float t = (vals[i]-m)*r*g[k] + b[k];
    if constexpr (FINAL){
      t = q[(size_t)row*DIMD + k] + gamma[k]*t;
    }
    out[(size_t)row*DIMD + k] = t;
  }
}

// ---------------- generic tiled GEMM: C = epi(A @ W^T + bias [+ res]) ----------------
// AMODE: 0 = A f32; 1 = A f32 with fused LayerNorm (stats + ag/ab); 2 = A bf16
// GELU_: apply tanh-gelu;  STBF: store bf16;  RES: add res[m*ldc+n]
template<int AMODE,int GELU_,int STBF,int RES>
__global__ __launch_bounds__(256) void gemm_k(
    const void* __restrict__ Av, const float* __restrict__ stats,
    const float* __restrict__ ag, const float* __restrict__ ab,
    const float* __restrict__ W, const float* __restrict__ bias,
    const float* __restrict__ res, void* __restrict__ Cv,
    int M, int N, int K, int ldc)
{
  constexpr int BM=64, BN=64, BK=16;
  __shared__ __align__(16) float As[BK][BM+4];
  __shared__ __align__(16) float Bs[BK][BN+4];
  const int tid = threadIdx.x;
  const int m0 = blockIdx.y*BM, n0 = blockIdx.x*BN;
  const int lr = tid>>2;          // 0..63 : row within tile
  const int lc = (tid&3)*4;       // 0,4,8,12 : k offset
  const int tm = (tid>>4)*4, tn = (tid&15)*4;
  const int am = m0+lr, wn = n0+lr;
  float acc[4][4] = {};
  for(int k0=0; k0<K; k0+=BK){
    float a4[4], w4[4];
    if(am < M){
      if constexpr (AMODE==2){
        const bf16* A = (const bf16*)Av;
        const bf16* p = A + (size_t)am*K + k0 + lc;
        a4[0]=__bfloat162float(p[0]); a4[1]=__bfloat162float(p[1]);
        a4[2]=__bfloat162float(p[2]); a4[3]=__bfloat162float(p[3]);
      } else {
        const float* A = (const float*)Av;
        float4 t = *(const float4*)(A + (size_t)am*K + k0 + lc);
        a4[0]=t.x; a4[1]=t.y; a4[2]=t.z; a4[3]=t.w;
        if constexpr (AMODE==1){
          float mu = stats[2*am], rs = stats[2*am+1];
          #pragma unroll
          for(int j=0;j<4;j++){ int k=k0+lc+j; a4[j] = (a4[j]-mu)*rs*ag[k] + ab[k]; }
        }
      }
    } else { a4[0]=a4[1]=a4[2]=a4[3]=0.f; }
    if(wn < N){
      float4 t = *(const float4*)(W + (size_t)wn*K + k0 + lc);
      w4[0]=t.x; w4[1]=t.y; w4[2]=t.z; w4[3]=t.w;
    } else { w4[0]=w4[1]=w4[2]=w4[3]=0.f; }
    #pragma unroll
    for(int j=0;j<4;j++){ As[lc+j][lr]=a4[j]; Bs[lc+j][lr]=w4[j]; }
    __syncthreads();
    #pragma unroll
    for(int k=0;k<BK;k++){
      float4 av = *(const float4*)&As[k][tm];
      float4 bv = *(const float4*)&Bs[k][tn];
      float aa[4]={av.x,av.y,av.z,av.w};
      float bb[4]={bv.x,bv.y,bv.z,bv.w};
      #pragma unroll
      for(int i=0;i<4;i++)
        #pragma unroll
        for(int j=0;j<4;j++)
          acc[i][j] = fmaf(aa[i], bb[j], acc[i][j]);
    }
    __syncthreads();
  }
  #pragma unroll
  for(int i=0;i<4;i++){
    int mm = m0+tm+i; if(mm>=M) continue;
    #pragma unroll
    for(int j=0;j<4;j++){
      int nn = n0+tn+j; if(nn>=N) continue;
      float v = acc[i][j] + bias[nn];
      if constexpr (RES)   v += res[(size_t)mm*ldc + nn];
      if constexpr (GELU_){ float u=v; v = 0.5f*u*(1.f+tanhf(0.7978845608028654f*(u+0.044715f*u*u*u))); }
      if constexpr (STBF)  ((bf16*)Cv)[(size_t)mm*ldc + nn] = __float2bfloat16(v);
      else                 ((float*)Cv)[(size_t)mm*ldc + nn] = v;
    }
  }
}

// ---------------- multi-scale deformable sampling ----------------
// one block per (b,q); wave w = head; lane = channel d. v is bf16 [B, NV, 384] head-major cols.
__global__ __launch_bounds__(384) void msda_sample_k(
    const bf16* __restrict__ v, const float* __restrict__ offaw,
    const float* __restrict__ refp, const int* __restrict__ sshapes,
    const int* __restrict__ lstart, float* __restrict__ out)
{
  const int bq = blockIdx.x;            // 0..MQ-1
  const int b  = bq / NQ;
  const int h  = threadIdx.x >> 6;
  const int lane = threadIdx.x & 63;
  const float* row = offaw + (size_t)bq*216;
  // softmax over the 12 attention logits of this head (lane-redundant, broadcast loads)
  float awv[12];
  float mx = -1e30f;
  #pragma unroll
  for(int i=0;i<12;i++){ awv[i] = row[144 + h*12 + i]; mx = fmaxf(mx, awv[i]); }
  float ssum = 0.f;
  #pragma unroll
  for(int i=0;i<12;i++){ awv[i] = __expf(awv[i]-mx); ssum += awv[i]; }
  const float inv = 1.f/ssum;
  float acc = 0.f;
  const bf16* vb = v + (size_t)b*NV*DIMD + h*DH + lane;
  #pragma unroll
  for(int l=0;l<LEVELS;l++){
    const int hh = sshapes[2*l], ww = sshapes[2*l+1];
    const int st = lstart[l];
    const float rx = refp[((size_t)bq*LEVELS + l)*2 + 0];
    const float ry = refp[((size_t)bq*LEVELS + l)*2 + 1];
    #pragma unroll
    for(int p=0;p<POINTS;p++){
      const float ox = row[((h*LEVELS + l)*POINTS + p)*2 + 0];
      const float oy = row[((h*LEVELS + l)*POINTS + p)*2 + 1];
      const float lx = rx + ox/(float)ww;
      const float ly = ry + oy/(float)hh;
      const float px = lx*(float)ww - 0.5f;
      const float py = ly*(float)hh - 0.5f;
      const float fx0 = floorf(px), fy0 = floorf(py);
      const int x0 = (int)fx0, y0 = (int)fy0;
      const float wx1 = px - fx0, wx0 = 1.f - wx1;
      const float wy1 = py - fy0, wy0 = 1.f - wy1;
      float cs = 0.f;
      #pragma unroll
      for(int c=0;c<4;c++){
        const int xi = x0 + (c&1);
        const int yi = y0 + (c>>1);
        const float wgt = (c&1 ? wx1 : wx0) * (c>>1 ? wy1 : wy0);
        const bool valid = (xi>=0) & (xi<=ww-1) & (yi>=0) & (yi<=hh-1);
        const int cx = min(max(xi,0), ww-1);
        const int cy = min(max(yi,0), hh-1);
        const float g = __bfloat162float(vb[(size_t)(st + cy*ww + cx)*DIMD]);
        cs += valid ? wgt*g : 0.f;
      }
      acc = fmaf(awv[l*POINTS+p]*inv, cs, acc);
    }
  }
  out[(size_t)bq*DIMD + h*DH + lane] = acc;
}

// ---------------- launcher ----------------
extern "C" void kernel_launch(void* const* d_in, const int* in_sizes, int n_in,
                              void* d_out, int out_size, void* d_ws, size_t ws_size,
                              hipStream_t stream)
{
  const float* query = (const float*)d_in[0];
  const float* refp  = (const float*)d_in[1];
  const float* feat  = (const float*)d_in[2];
  const int*   sshp  = (const int*)d_in[3];
  const int*   lst   = (const int*)d_in[4];
  const float* qn_g  = (const float*)d_in[5];
  const float* qn_b  = (const float*)d_in[6];
  const float* fn_g  = (const float*)d_in[7];
  const float* fn_b  = (const float*)d_in[8];
  const float* W_off = (const float*)d_in[9];
  const float* b_off = (const float*)d_in[10];
  const float* W_aw  = (const float*)d_in[11];
  const float* b_aw  = (const float*)d_in[12];
  const float* W_v   = (const float*)d_in[13];
  const float* b_v   = (const float*)d_in[14];
  const float* W_o   = (const float*)d_in[15];
  const float* b_o   = (const float*)d_in[16];
  const float* n1_g  = (const float*)d_in[17];
  const float* n1_b  = (const float*)d_in[18];
  const float* W1    = (const float*)d_in[19];
  const float* b1    = (const float*)d_in[20];
  const float* W2    = (const float*)d_in[21];
  const float* b2    = (const float*)d_in[22];
  const float* n2_g  = (const float*)d_in[23];
  const float* n2_b  = (const float*)d_in[24];
  const float* gam   = (const float*)d_in[25];

  // workspace layout (~215 MB total)
  char* p = (char*)d_ws;
  float* qn    = (float*)p;  p += (size_t)MQ*DIMD*4;
  float* stats = (float*)p;  p += (size_t)MV*2*4;
  bf16*  vbuf  = (bf16*)p;   p += (size_t)MV*DIMD*2;
  float* offaw = (float*)p;  p += (size_t)MQ*216*4;
  float* msda  = (float*)p;  p += (size_t)MQ*DIMD*4;
  float* x1    = (float*)p;  p += (size_t)MQ*DIMD*4;
  float* x2    = (float*)p;  p += (size_t)MQ*DIMD*4;
  bf16*  hbuf  = (bf16*)p;   p += (size_t)MQ*FFN*2;

  // 1. feat row stats (LN fused into value-proj GEMM A-load)
  row_stats_k<<<MV/4, 256, 0, stream>>>(feat, stats, MV);
  // 2. qn = LN(query)
  row_ln_k<0><<<MQ/4, 256, 0, stream>>>(query, qn_g, qn_b, nullptr, nullptr, qn, MQ);
  // 3. v = LN(feat) @ W_v^T + b_v   (bf16 store)
  gemm_k<1,0,1,0><<<dim3(DIMD/64, MV/64), 256, 0, stream>>>(
      feat, stats, fn_g, fn_b, W_v, b_v, nullptr, vbuf, MV, DIMD, DIMD, DIMD);
  // 4. offsets = qn @ W_off^T + b_off  -> offaw cols [0,144)
  gemm_k<0,0,0,0><<<dim3(3, MQ/64), 256, 0, stream>>>(
      qn, nullptr, nullptr, nullptr, W_off, b_off, nullptr, offaw, MQ, 144, DIMD, 216);
  // 5. aw logits = qn @ W_aw^T + b_aw  -> offaw cols [144,216)
  gemm_k<0,0,0,0><<<dim3(2, MQ/64), 256, 0, stream>>>(
      qn, nullptr, nullptr, nullptr, W_aw, b_aw, nullptr, offaw+144, MQ, 72, DIMD, 216);
  // 6. deformable sampling (softmax fused) -> msda [MQ,384]
  msda_sample_k<<<MQ, 384, 0, stream>>>(vbuf, offaw, refp, sshp, lst, msda);
  // 7. x1 = qn + msda @ W_o^T + b_o
  gemm_k<0,0,0,1><<<dim3(DIMD/64, MQ/64), 256, 0, stream>>>(
      msda, nullptr, nullptr, nullptr, W_o, b_o, qn, x1, MQ, DIMD, DIMD, DIMD);
  // 8. x2 = LN(x1)
  row_ln_k<0><<<MQ/4, 256, 0, stream>>>(x1, n1_g, n1_b, nullptr, nullptr, x2, MQ);
  // 9. h = gelu(x2 @ W1^T + b1)   (bf16 store)
  gemm_k<0,1,1,0><<<dim3(FFN/64, MQ/64), 256, 0, stream>>>(
      x2, nullptr, nullptr, nullptr, W1, b1, nullptr, hbuf, MQ, FFN, DIMD, FFN);
  // 10. y = x2 + h @ W2^T + b2   (reuse x1)
  gemm_k<2,0,0,1><<<dim3(DIMD/64, MQ/64), 256, 0, stream>>>(
      hbuf, nullptr, nullptr, nullptr, W2, b2, x2, x1, MQ, DIMD, FFN, DIMD);
  // 11. out = query + gamma * LN(y)
  row_ln_k<1><<<MQ/4, 256, 0, stream>>>(x1, n2_g, n2_b, query, gam, (float*)d_out, MQ);
}

// Round 2
// 400.157 us; speedup vs baseline: 2.8259x; 2.8259x over previous
//
#include <hip/hip_runtime.h>
#include <hip/hip_bf16.h>

// ---------------- problem constants ----------------
#define DIMD 384
#define HEADS 6
#define DH 64
#define LEVELS 3
#define POINTS 4
#define FFN 1024
#define BB 4
#define NQ 4096
#define NV 21504
#define MQ (BB*NQ)   // 16384
#define MV (BB*NV)   // 86016
#define EPSF 1e-6f

typedef __hip_bfloat16 bf16;
typedef __attribute__((ext_vector_type(8))) short bf16x8;
typedef __attribute__((ext_vector_type(4))) float f32x4;

__device__ __forceinline__ float wave_sum(float v){
  #pragma unroll
  for(int o=32;o;o>>=1) v += __shfl_xor(v,o);
  return v;
}

// ---------------- weight prep: fp32 -> bf16 (+ concat/pad W_off|W_aw to 256 rows) ----------------
__global__ __launch_bounds__(256) void prep_k(
  const float* __restrict__ Wv, const float* __restrict__ Wo,
  const float* __restrict__ W1, const float* __restrict__ W2,
  const float* __restrict__ Woff, const float* __restrict__ Waw,
  const float* __restrict__ boff, const float* __restrict__ baw,
  bf16* __restrict__ wv, bf16* __restrict__ wo, bf16* __restrict__ w1,
  bf16* __restrict__ w2, bf16* __restrict__ wcat, float* __restrict__ bcat)
{
  int i = blockIdx.x*256 + threadIdx.x;
  if(i < 147456){ wv[i] = __float2bfloat16(Wv[i]); return; }
  i -= 147456;
  if(i < 147456){ wo[i] = __float2bfloat16(Wo[i]); return; }
  i -= 147456;
  if(i < 393216){ w1[i] = __float2bfloat16(W1[i]); return; }
  i -= 393216;
  if(i < 393216){ w2[i] = __float2bfloat16(W2[i]); return; }
  i -= 393216;
  if(i < 98304){
    int r = i/384, c = i - r*384;
    float v = r<144 ? Woff[r*384+c] : (r<216 ? Waw[(r-144)*384+c] : 0.f);
    wcat[i] = __float2bfloat16(v); return;
  }
  i -= 98304;
  if(i < 256){ bcat[i] = i<144 ? boff[i] : (i<216 ? baw[i-144] : 0.f); }
}

// ---------------- row LayerNorm (DIMD=384), templated in/out dtype ----------------
// FINAL=1: out = q + gamma * LN(x)   (fp32 out)
template<int INBF,int OUTBF,int FINAL>
__global__ __launch_bounds__(256) void ln_k(const void* __restrict__ xv,
    const float* __restrict__ g, const float* __restrict__ b,
    const float* __restrict__ q, const float* __restrict__ gamma,
    void* __restrict__ outv, int nrows)
{
  int row = blockIdx.x*4 + (threadIdx.x>>6);
  int lane = threadIdx.x & 63;
  if(row >= nrows) return;
  float vals[6];
  float s=0.f, s2=0.f;
  #pragma unroll
  for(int i=0;i<6;i++){
    float v;
    if constexpr(INBF) v = __bfloat162float(((const bf16*)xv)[(size_t)row*DIMD + lane + i*64]);
    else               v = ((const float*)xv)[(size_t)row*DIMD + lane + i*64];
    vals[i]=v; s += v; s2 += v*v;
  }
  s = wave_sum(s); s2 = wave_sum(s2);
  float m = s*(1.f/DIMD);
  float var = s2*(1.f/DIMD) - m*m;
  float r = rsqrtf(var + EPSF);
  #pragma unroll
  for(int i=0;i<6;i++){
    int k = lane + i*64;
    float t = (vals[i]-m)*r*g[k] + b[k];
    if constexpr(FINAL){
      t = q[(size_t)row*DIMD + k] + gamma[k]*t;
      ((float*)outv)[(size_t)row*DIMD + k] = t;
    } else if constexpr(OUTBF){
      ((bf16*)outv)[(size_t)row*DIMD + k] = __float2bfloat16(t);
    } else {
      ((float*)outv)[(size_t)row*DIMD + k] = t;
    }
  }
}

// ---------------- bf16 MFMA GEMM: C = epi(A @ W^T + bias [+ res]) ----------------
// A: [M][K] bf16 row-major; W: [Npad][K] bf16 row-major; 128x128 tile, BK=64.
// 256 threads = 4 waves (2x2), each wave 64x64 via 4x4 frags of 16x16x32.
template<int GELU_,int STBF,int RES>
__global__ __launch_bounds__(256) void mgemm_k(
    const bf16* __restrict__ A, const bf16* __restrict__ Bw,
    const float* __restrict__ bias, const bf16* __restrict__ res,
    void* __restrict__ Cv, int M, int K, int Nreal, int ldc)
{
  __shared__ __align__(16) short As[128*64];
  __shared__ __align__(16) short Bs[128*64];
  const int tid  = threadIdx.x;
  const int wid  = tid>>6, lane = tid&63;
  const int wr   = wid>>1, wc = wid&1;
  const int m0   = blockIdx.y*128, n0 = blockIdx.x*128;
  f32x4 acc[4][4] = {};

  const int sr = (lane>>3);      // 0..7  row-within-8 for staging
  const int sc = (lane&7)*8;     // element offset within BK row

  for(int k0=0; k0<K; k0+=64){
    #pragma unroll
    for(int u=0;u<4;u++){
      const int t = wid*4 + u;             // 0..15 staging instr
      const int r = t*8 + sr;              // tile row 0..127
      const bf16* srcA = A  + (size_t)(m0+r)*K + k0 + sc;
      const bf16* srcB = Bw + (size_t)(n0+r)*K + k0 + sc;
      __builtin_amdgcn_global_load_lds((const __attribute__((address_space(1))) void*)srcA,
          (__attribute__((address_space(3))) void*)(As + t*512), 16, 0, 0);
      __builtin_amdgcn_global_load_lds((const __attribute__((address_space(1))) void*)srcB,
          (__attribute__((address_space(3))) void*)(Bs + t*512), 16, 0, 0);
    }
    asm volatile("s_waitcnt vmcnt(0)" ::: "memory");
    __syncthreads();
    #pragma unroll
    for(int ks=0;ks<2;ks++){
      bf16x8 af[4], bfr[4];
      #pragma unroll
      for(int i=0;i<4;i++){
        const int ar = wr*64 + i*16 + (lane&15);
        af[i]  = *(const bf16x8*)(As + ar*64 + ks*32 + (lane>>4)*8);
        const int br = wc*64 + i*16 + (lane&15);
        bfr[i] = *(const bf16x8*)(Bs + br*64 + ks*32 + (lane>>4)*8);
      }
      #pragma unroll
      for(int i=0;i<4;i++)
        #pragma unroll
        for(int j=0;j<4;j++)
          acc[i][j] = __builtin_amdgcn_mfma_f32_16x16x32_bf16(af[i], bfr[j], acc[i][j], 0,0,0);
    }
    __syncthreads();
  }
  // epilogue: C row = m0+wr*64+i*16+(lane>>4)*4+reg, col = n0+wc*64+j*16+(lane&15)
  #pragma unroll
  for(int i=0;i<4;i++){
    const int rbase = m0 + wr*64 + i*16 + (lane>>4)*4;
    #pragma unroll
    for(int j=0;j<4;j++){
      const int col = n0 + wc*64 + j*16 + (lane&15);
      if(col >= Nreal) continue;
      const float bv = bias[col];
      #pragma unroll
      for(int rr=0;rr<4;rr++){
        const int rowg = rbase + rr;
        float v = acc[i][j][rr] + bv;
        if constexpr(RES) v += __bfloat162float(res[(size_t)rowg*ldc + col]);
        if constexpr(GELU_){ float u=v; v = 0.5f*u*(1.f+tanhf(0.7978845608028654f*(u+0.044715f*u*u*u))); }
        if constexpr(STBF) ((bf16*)Cv)[(size_t)rowg*ldc + col] = __float2bfloat16(v);
        else               ((float*)Cv)[(size_t)rowg*ldc + col] = v;
      }
    }
  }
}

// ---------------- multi-scale deformable sampling (softmax fused) ----------------
__global__ __launch_bounds__(384) void msda_sample_k(
    const bf16* __restrict__ v, const float* __restrict__ offaw,
    const float* __restrict__ refp, const int* __restrict__ sshapes,
    const int* __restrict__ lstart, bf16* __restrict__ out)
{
  const int bq = blockIdx.x;            // 0..MQ-1
  const int b  = bq / NQ;
  const int h  = threadIdx.x >> 6;
  const int lane = threadIdx.x & 63;
  const float* row = offaw + (size_t)bq*216;
  float awv[12];
  float mx = -1e30f;
  #pragma unroll
  for(int i=0;i<12;i++){ awv[i] = row[144 + h*12 + i]; mx = fmaxf(mx, awv[i]); }
  float ssum = 0.f;
  #pragma unroll
  for(int i=0;i<12;i++){ awv[i] = __expf(awv[i]-mx); ssum += awv[i]; }
  const float inv = 1.f/ssum;
  float acc = 0.f;
  const bf16* vb = v + (size_t)b*NV*DIMD + h*DH + lane;
  #pragma unroll
  for(int l=0;l<LEVELS;l++){
    const int hh = sshapes[2*l], ww = sshapes[2*l+1];
    const int st = lstart[l];
    const float rx = refp[((size_t)bq*LEVELS + l)*2 + 0];
    const float ry = refp[((size_t)bq*LEVELS + l)*2 + 1];
    #pragma unroll
    for(int p=0;p<POINTS;p++){
      const float ox = row[((h*LEVELS + l)*POINTS + p)*2 + 0];
      const float oy = row[((h*LEVELS + l)*POINTS + p)*2 + 1];
      const float px = (rx + ox/(float)ww)*(float)ww - 0.5f;
      const float py = (ry + oy/(float)hh)*(float)hh - 0.5f;
      const float fx0 = floorf(px), fy0 = floorf(py);
      const int x0 = (int)fx0, y0 = (int)fy0;
      const float wx1 = px - fx0, wx0 = 1.f - wx1;
      const float wy1 = py - fy0, wy0 = 1.f - wy1;
      float cs = 0.f;
      #pragma unroll
      for(int c=0;c<4;c++){
        const int xi = x0 + (c&1);
        const int yi = y0 + (c>>1);
        const float wgt = (c&1 ? wx1 : wx0) * (c>>1 ? wy1 : wy0);
        const bool valid = (xi>=0) & (xi<=ww-1) & (yi>=0) & (yi<=hh-1);
        const int cx = min(max(xi,0), ww-1);
        const int cy = min(max(yi,0), hh-1);
        const float g = __bfloat162float(vb[(size_t)(st + cy*ww + cx)*DIMD]);
        cs += valid ? wgt*g : 0.f;
      }
      acc = fmaf(awv[l*POINTS+p]*inv, cs, acc);
    }
  }
  out[(size_t)bq*DIMD + h*DH + lane] = __float2bfloat16(acc);
}

// ---------------- launcher ----------------
static inline size_t rnd(size_t x){ return (x + 511) & ~(size_t)511; }

extern "C" void kernel_launch(void* const* d_in, const int* in_sizes, int n_in,
                              void* d_out, int out_size, void* d_ws, size_t ws_size,
                              hipStream_t stream)
{
  const float* query = (const float*)d_in[0];
  const float* refp  = (const float*)d_in[1];
  const float* feat  = (const float*)d_in[2];
  const int*   sshp  = (const int*)d_in[3];
  const int*   lst   = (const int*)d_in[4];
  const float* qn_g  = (const float*)d_in[5];
  const float* qn_b  = (const float*)d_in[6];
  const float* fn_g  = (const float*)d_in[7];
  const float* fn_b  = (const float*)d_in[8];
  const float* W_off = (const float*)d_in[9];
  const float* b_off = (const float*)d_in[10];
  const float* W_aw  = (const float*)d_in[11];
  const float* b_aw  = (const float*)d_in[12];
  const float* W_v   = (const float*)d_in[13];
  const float* b_v   = (const float*)d_in[14];
  const float* W_o   = (const float*)d_in[15];
  const float* b_o   = (const float*)d_in[16];
  const float* n1_g  = (const float*)d_in[17];
  const float* n1_b  = (const float*)d_in[18];
  const float* W1    = (const float*)d_in[19];
  const float* b1    = (const float*)d_in[20];
  const float* W2    = (const float*)d_in[21];
  const float* b2    = (const float*)d_in[22];
  const float* n2_g  = (const float*)d_in[23];
  const float* n2_b  = (const float*)d_in[24];
  const float* gam   = (const float*)d_in[25];

  // ---- workspace layout (aliased; ~193 MB) ----
  char* p = (char*)d_ws;
  bf16* featn = (bf16*)p;                      // [MV][384] bf16, dead after v-proj
  char* late  = p;                             // aliased region reused after step 4
  p += rnd((size_t)MV*DIMD*2);
  bf16* vbuf  = (bf16*)p;  p += rnd((size_t)MV*DIMD*2);
  bf16* qn    = (bf16*)p;  p += rnd((size_t)MQ*DIMD*2);
  bf16* wv    = (bf16*)p;  p += rnd((size_t)147456*2);
  bf16* wo    = (bf16*)p;  p += rnd((size_t)147456*2);
  bf16* w1    = (bf16*)p;  p += rnd((size_t)393216*2);
  bf16* w2    = (bf16*)p;  p += rnd((size_t)393216*2);
  bf16* wcat  = (bf16*)p;  p += rnd((size_t)98304*2);
  float* bcat = (float*)p; p += rnd((size_t)256*4);
  bf16* hbuf  = (bf16*)p;  p += rnd((size_t)MQ*FFN*2);
  bf16* ybuf  = (bf16*)p;  p += rnd((size_t)MQ*DIMD*2);
  // late-region carve (all used only after featn is dead)
  char* q2 = late;
  float* offaw = (float*)q2; q2 += rnd((size_t)MQ*216*4);
  bf16*  msda  = (bf16*)q2;  q2 += rnd((size_t)MQ*DIMD*2);
  bf16*  x1    = (bf16*)q2;  q2 += rnd((size_t)MQ*DIMD*2);
  bf16*  x2    = (bf16*)q2;  q2 += rnd((size_t)MQ*DIMD*2);

  // 1. weights -> bf16 (+concat/pad)
  prep_k<<<4609, 256, 0, stream>>>(W_v, W_o, W1, W2, W_off, W_aw, b_off, b_aw,
                                   wv, wo, w1, w2, wcat, bcat);
  // 2. featn = LN(feat) bf16 ; qn = LN(query) bf16
  ln_k<0,1,0><<<MV/4, 256, 0, stream>>>(feat, fn_g, fn_b, nullptr, nullptr, featn, MV);
  ln_k<0,1,0><<<MQ/4, 256, 0, stream>>>(query, qn_g, qn_b, nullptr, nullptr, qn, MQ);
  // 3. v = featn @ W_v^T + b_v  (bf16)
  mgemm_k<0,1,0><<<dim3(3, MV/128), 256, 0, stream>>>(featn, wv, b_v, nullptr, vbuf,
                                                      MV, DIMD, DIMD, DIMD);
  // 4. offsets|logits = qn @ Wcat^T + bcat  (fp32, ldc 216, Npad 256)
  mgemm_k<0,0,0><<<dim3(2, MQ/128), 256, 0, stream>>>(qn, wcat, bcat, nullptr, offaw,
                                                      MQ, DIMD, 216, 216);
  // 5. deformable sampling -> msda bf16
  msda_sample_k<<<MQ, 384, 0, stream>>>(vbuf, offaw, refp, sshp, lst, msda);
  // 6. x1 = qn + msda @ W_o^T + b_o  (bf16)
  mgemm_k<0,1,1><<<dim3(3, MQ/128), 256, 0, stream>>>(msda, wo, b_o, qn, x1,
                                                      MQ, DIMD, DIMD, DIMD);
  // 7. x2 = LN(x1) bf16
  ln_k<1,1,0><<<MQ/4, 256, 0, stream>>>(x1, n1_g, n1_b, nullptr, nullptr, x2, MQ);
  // 8. h = gelu(x2 @ W1^T + b1)  (bf16)
  mgemm_k<1,1,0><<<dim3(8, MQ/128), 256, 0, stream>>>(x2, w1, b1, nullptr, hbuf,
                                                      MQ, DIMD, FFN, FFN);
  // 9. y = x2 + h @ W2^T + b2  (bf16)
  mgemm_k<0,1,1><<<dim3(3, MQ/128), 256, 0, stream>>>(hbuf, w2, b2, x2, ybuf,
                                                      MQ, FFN, DIMD, DIMD);
  // 10. out = query + gamma * LN(y)
  ln_k<1,0,1><<<MQ/4, 256, 0, stream>>>(ybuf, n2_g, n2_b, query, gam, (float*)d_out, MQ);
}

// Round 3
// 312.601 us; speedup vs baseline: 3.6174x; 1.2801x over previous
//
#include <hip/hip_runtime.h>
#include <hip/hip_bf16.h>

// ---------------- problem constants ----------------
#define DIMD 384
#define HEADS 6
#define DH 64
#define LEVELS 3
#define POINTS 4
#define FFN 1024
#define BB 4
#define NQ 4096
#define NV 21504
#define MQ (BB*NQ)   // 16384
#define MV (BB*NV)   // 86016
#define EPSF 1e-6f

typedef __hip_bfloat16 bf16;
typedef __attribute__((ext_vector_type(8))) short bf16x8;
typedef __attribute__((ext_vector_type(4))) float f32x4;

__device__ __forceinline__ float wave_sum(float v){
  #pragma unroll
  for(int o=32;o;o>>=1) v += __shfl_xor(v,o);
  return v;
}

// ---------------- weight prep: fp32 -> bf16 (+ concat/pad W_off|W_aw to 256 rows) ----------------
__global__ __launch_bounds__(256) void prep_k(
  const float* __restrict__ Wv, const float* __restrict__ Wo,
  const float* __restrict__ W1, const float* __restrict__ W2,
  const float* __restrict__ Woff, const float* __restrict__ Waw,
  const float* __restrict__ boff, const float* __restrict__ baw,
  bf16* __restrict__ wv, bf16* __restrict__ wo, bf16* __restrict__ w1,
  bf16* __restrict__ w2, bf16* __restrict__ wcat, float* __restrict__ bcat)
{
  int i = blockIdx.x*256 + threadIdx.x;
  if(i < 147456){ wv[i] = __float2bfloat16(Wv[i]); return; }
  i -= 147456;
  if(i < 147456){ wo[i] = __float2bfloat16(Wo[i]); return; }
  i -= 147456;
  if(i < 393216){ w1[i] = __float2bfloat16(W1[i]); return; }
  i -= 393216;
  if(i < 393216){ w2[i] = __float2bfloat16(W2[i]); return; }
  i -= 393216;
  if(i < 98304){
    int r = i/384, c = i - r*384;
    float v = r<144 ? Woff[r*384+c] : (r<216 ? Waw[(r-144)*384+c] : 0.f);
    wcat[i] = __float2bfloat16(v); return;
  }
  i -= 98304;
  if(i < 256){ bcat[i] = i<144 ? boff[i] : (i<216 ? baw[i-144] : 0.f); }
}

// ---------------- row LayerNorm (DIMD=384), templated in/out dtype ----------------
// FINAL=1: out = q + gamma * LN(x)   (fp32 out)
template<int INBF,int OUTBF,int FINAL>
__global__ __launch_bounds__(256) void ln_k(const void* __restrict__ xv,
    const float* __restrict__ g, const float* __restrict__ b,
    const float* __restrict__ q, const float* __restrict__ gamma,
    void* __restrict__ outv, int nrows)
{
  int row = blockIdx.x*4 + (threadIdx.x>>6);
  int lane = threadIdx.x & 63;
  if(row >= nrows) return;
  float vals[6];
  float s=0.f, s2=0.f;
  #pragma unroll
  for(int i=0;i<6;i++){
    float v;
    if constexpr(INBF) v = __bfloat162float(((const bf16*)xv)[(size_t)row*DIMD + lane + i*64]);
    else               v = ((const float*)xv)[(size_t)row*DIMD + lane + i*64];
    vals[i]=v; s += v; s2 += v*v;
  }
  s = wave_sum(s); s2 = wave_sum(s2);
  float m = s*(1.f/DIMD);
  float var = s2*(1.f/DIMD) - m*m;
  float r = rsqrtf(var + EPSF);
  #pragma unroll
  for(int i=0;i<6;i++){
    int k = lane + i*64;
    float t = (vals[i]-m)*r*g[k] + b[k];
    if constexpr(FINAL){
      t = q[(size_t)row*DIMD + k] + gamma[k]*t;
      ((float*)outv)[(size_t)row*DIMD + k] = t;
    } else if constexpr(OUTBF){
      ((bf16*)outv)[(size_t)row*DIMD + k] = __float2bfloat16(t);
    } else {
      ((float*)outv)[(size_t)row*DIMD + k] = t;
    }
  }
}

// ---------------- bf16 MFMA GEMM: C = epi(A @ W^T + bias [+ res]) ----------------
template<int GELU_,int STBF,int RES>
__global__ __launch_bounds__(256) void mgemm_k(
    const bf16* __restrict__ A, const bf16* __restrict__ Bw,
    const float* __restrict__ bias, const bf16* __restrict__ res,
    void* __restrict__ Cv, int M, int K, int Nreal, int ldc)
{
  __shared__ __align__(16) short As[128*64];
  __shared__ __align__(16) short Bs[128*64];
  const int tid  = threadIdx.x;
  const int wid  = tid>>6, lane = tid&63;
  const int wr   = wid>>1, wc = wid&1;
  const int m0   = blockIdx.y*128, n0 = blockIdx.x*128;
  f32x4 acc[4][4] = {};

  const int sr = (lane>>3);      // 0..7  row-within-8 for staging
  const int sc = (lane&7)*8;     // element offset within BK row

  for(int k0=0; k0<K; k0+=64){
    #pragma unroll
    for(int u=0;u<4;u++){
      const int t = wid*4 + u;             // 0..15 staging instr
      const int r = t*8 + sr;              // tile row 0..127
      const bf16* srcA = A  + (size_t)(m0+r)*K + k0 + sc;
      const bf16* srcB = Bw + (size_t)(n0+r)*K + k0 + sc;
      __builtin_amdgcn_global_load_lds((const __attribute__((address_space(1))) void*)srcA,
          (__attribute__((address_space(3))) void*)(As + t*512), 16, 0, 0);
      __builtin_amdgcn_global_load_lds((const __attribute__((address_space(1))) void*)srcB,
          (__attribute__((address_space(3))) void*)(Bs + t*512), 16, 0, 0);
    }
    asm volatile("s_waitcnt vmcnt(0)" ::: "memory");
    __syncthreads();
    #pragma unroll
    for(int ks=0;ks<2;ks++){
      bf16x8 af[4], bfr[4];
      #pragma unroll
      for(int i=0;i<4;i++){
        const int ar = wr*64 + i*16 + (lane&15);
        af[i]  = *(const bf16x8*)(As + ar*64 + ks*32 + (lane>>4)*8);
        const int br = wc*64 + i*16 + (lane&15);
        bfr[i] = *(const bf16x8*)(Bs + br*64 + ks*32 + (lane>>4)*8);
      }
      #pragma unroll
      for(int i=0;i<4;i++)
        #pragma unroll
        for(int j=0;j<4;j++)
          acc[i][j] = __builtin_amdgcn_mfma_f32_16x16x32_bf16(af[i], bfr[j], acc[i][j], 0,0,0);
    }
    __syncthreads();
  }
  #pragma unroll
  for(int i=0;i<4;i++){
    const int rbase = m0 + wr*64 + i*16 + (lane>>4)*4;
    #pragma unroll
    for(int j=0;j<4;j++){
      const int col = n0 + wc*64 + j*16 + (lane&15);
      if(col >= Nreal) continue;
      const float bv = bias[col];
      #pragma unroll
      for(int rr=0;rr<4;rr++){
        const int rowg = rbase + rr;
        float v = acc[i][j][rr] + bv;
        if constexpr(RES) v += __bfloat162float(res[(size_t)rowg*ldc + col]);
        if constexpr(GELU_){ float u=v; v = 0.5f*u*(1.f+tanhf(0.7978845608028654f*(u+0.044715f*u*u*u))); }
        if constexpr(STBF) ((bf16*)Cv)[(size_t)rowg*ldc + col] = __float2bfloat16(v);
        else               ((float*)Cv)[(size_t)rowg*ldc + col] = v;
      }
    }
  }
}

// ---------------- MSDA point prep: one THREAD per (bq, head) ----------------
// Emits 48 {u32 byte-offset into v, f32 weight} pairs per (bq,h); attention
// softmax weight folded into the bilinear corner weight; invalid corners get w=0.
__global__ __launch_bounds__(256) void msda_prep_k(
    const float* __restrict__ offaw, const float* __restrict__ refp,
    const int* __restrict__ sshapes, const int* __restrict__ lstart,
    uint2* __restrict__ pairs)
{
  const int t = blockIdx.x*256 + threadIdx.x;
  if(t >= MQ*HEADS) return;
  const int bq = t/6, h = t - bq*6;
  const int b  = bq >> 12;                 // bq / NQ
  const float* row = offaw + (size_t)bq*216;
  float awv[12];
  float mx = -1e30f;
  #pragma unroll
  for(int i=0;i<12;i++){ awv[i] = row[144 + h*12 + i]; mx = fmaxf(mx, awv[i]); }
  float ssum = 0.f;
  #pragma unroll
  for(int i=0;i<12;i++){ awv[i] = __expf(awv[i]-mx); ssum += awv[i]; }
  const float inv = 1.f/ssum;
  uint2* pw = pairs + (size_t)t*48;
  int c48 = 0;
  #pragma unroll
  for(int l=0;l<LEVELS;l++){
    const int hh = sshapes[2*l], ww = sshapes[2*l+1];
    const int st = lstart[l];
    const float rx = refp[((size_t)bq*LEVELS + l)*2 + 0];
    const float ry = refp[((size_t)bq*LEVELS + l)*2 + 1];
    #pragma unroll
    for(int p=0;p<POINTS;p++){
      const float ox = row[((h*LEVELS + l)*POINTS + p)*2 + 0];
      const float oy = row[((h*LEVELS + l)*POINTS + p)*2 + 1];
      const float px = (rx + ox/(float)ww)*(float)ww - 0.5f;
      const float py = (ry + oy/(float)hh)*(float)hh - 0.5f;
      const float fx0 = floorf(px), fy0 = floorf(py);
      const int x0 = (int)fx0, y0 = (int)fy0;
      const float wx1 = px - fx0, wx0 = 1.f - wx1;
      const float wy1 = py - fy0, wy0 = 1.f - wy1;
      const float aww = awv[l*POINTS+p]*inv;
      #pragma unroll
      for(int c=0;c<4;c++){
        const int xi = x0 + (c&1);
        const int yi = y0 + (c>>1);
        const float wgt = (c&1 ? wx1 : wx0) * (c>>1 ? wy1 : wy0);
        const bool valid = (xi>=0) & (xi<=ww-1) & (yi>=0) & (yi<=hh-1);
        const int cx = min(max(xi,0), ww-1);
        const int cy = min(max(yi,0), hh-1);
        const unsigned off = (unsigned)((((b*NV + st + cy*ww + cx)*DIMD) + h*DH)*2);
        const float w = valid ? wgt*aww : 0.f;
        uint2 pr; pr.x = off; pr.y = __float_as_uint(w);
        pw[c48++] = pr;
      }
    }
  }
}

// ---------------- MSDA gather: half-wave (32 lanes) per (bq,h), 2 ch/lane ----------------
__global__ __launch_bounds__(256) void msda_gather_k(
    const bf16* __restrict__ v, const uint2* __restrict__ pairs,
    bf16* __restrict__ out)
{
  const int wid  = blockIdx.x*4 + (threadIdx.x>>6);
  const int lane = threadIdx.x & 63;
  const int pid  = wid*2 + (lane>>5);      // (bq,h) index
  const int ch   = lane & 31;              // channel-pair index
  const uint2* pw = pairs + (size_t)pid*48;
  const char* vb = (const char*)v;
  float a0 = 0.f, a1 = 0.f;
  #pragma unroll
  for(int c=0;c<48;c++){
    const uint2 pr = pw[c];
    const unsigned g = *(const unsigned*)(vb + pr.x + (ch<<2));
    const float w = __uint_as_float(pr.y);
    const float lo = __uint_as_float(g << 16);
    const float hi = __uint_as_float(g & 0xffff0000u);
    a0 = fmaf(w, lo, a0);
    a1 = fmaf(w, hi, a1);
  }
  const int bq = pid/6, h = pid - bq*6;
  const unsigned u0 = (unsigned)__builtin_bit_cast(unsigned short, __float2bfloat16(a0));
  const unsigned u1 = (unsigned)__builtin_bit_cast(unsigned short, __float2bfloat16(a1));
  *(unsigned*)((char*)out + (size_t)bq*768 + h*128 + (ch<<2)) = u0 | (u1<<16);
}

// ---------------- launcher ----------------
static inline size_t rnd(size_t x){ return (x + 511) & ~(size_t)511; }

extern "C" void kernel_launch(void* const* d_in, const int* in_sizes, int n_in,
                              void* d_out, int out_size, void* d_ws, size_t ws_size,
                              hipStream_t stream)
{
  const float* query = (const float*)d_in[0];
  const float* refp  = (const float*)d_in[1];
  const float* feat  = (const float*)d_in[2];
  const int*   sshp  = (const int*)d_in[3];
  const int*   lst   = (const int*)d_in[4];
  const float* qn_g  = (const float*)d_in[5];
  const float* qn_b  = (const float*)d_in[6];
  const float* fn_g  = (const float*)d_in[7];
  const float* fn_b  = (const float*)d_in[8];
  const float* W_off = (const float*)d_in[9];
  const float* b_off = (const float*)d_in[10];
  const float* W_aw  = (const float*)d_in[11];
  const float* b_aw  = (const float*)d_in[12];
  const float* W_v   = (const float*)d_in[13];
  const float* b_v   = (const float*)d_in[14];
  const float* W_o   = (const float*)d_in[15];
  const float* b_o   = (const float*)d_in[16];
  const float* n1_g  = (const float*)d_in[17];
  const float* n1_b  = (const float*)d_in[18];
  const float* W1    = (const float*)d_in[19];
  const float* b1    = (const float*)d_in[20];
  const float* W2    = (const float*)d_in[21];
  const float* b2    = (const float*)d_in[22];
  const float* n2_g  = (const float*)d_in[23];
  const float* n2_b  = (const float*)d_in[24];
  const float* gam   = (const float*)d_in[25];

  // ---- workspace layout (aliased; ~193 MB) ----
  char* p = (char*)d_ws;
  bf16* featn = (bf16*)p;                      // [MV][384] bf16, dead after v-proj
  char* late  = p;                             // aliased region reused after step 4
  p += rnd((size_t)MV*DIMD*2);
  bf16* vbuf  = (bf16*)p;  p += rnd((size_t)MV*DIMD*2);
  bf16* qn    = (bf16*)p;  p += rnd((size_t)MQ*DIMD*2);
  bf16* wv    = (bf16*)p;  p += rnd((size_t)147456*2);
  bf16* wo    = (bf16*)p;  p += rnd((size_t)147456*2);
  bf16* w1    = (bf16*)p;  p += rnd((size_t)393216*2);
  bf16* w2    = (bf16*)p;  p += rnd((size_t)393216*2);
  bf16* wcat  = (bf16*)p;  p += rnd((size_t)98304*2);
  float* bcat = (float*)p; p += rnd((size_t)256*4);
  bf16* hbuf  = (bf16*)p;  p += rnd((size_t)MQ*FFN*2);
  bf16* ybuf  = (bf16*)p;  p += rnd((size_t)MQ*DIMD*2);
  // late-region carve (used only after featn is dead)
  char* q2 = late;
  float* offaw = (float*)q2; q2 += rnd((size_t)MQ*216*4);
  bf16*  msda  = (bf16*)q2;  q2 += rnd((size_t)MQ*DIMD*2);
  bf16*  x1    = (bf16*)q2;  q2 += rnd((size_t)MQ*DIMD*2);
  bf16*  x2    = (bf16*)q2;  q2 += rnd((size_t)MQ*DIMD*2);
  // pairs table (37.7 MB) aliases hbuf+ybuf (both dead until FFN steps)
  uint2* pairs = (uint2*)hbuf;

  // 1. weights -> bf16 (+concat/pad)
  prep_k<<<4609, 256, 0, stream>>>(W_v, W_o, W1, W2, W_off, W_aw, b_off, b_aw,
                                   wv, wo, w1, w2, wcat, bcat);
  // 2. featn = LN(feat) bf16 ; qn = LN(query) bf16
  ln_k<0,1,0><<<MV/4, 256, 0, stream>>>(feat, fn_g, fn_b, nullptr, nullptr, featn, MV);
  ln_k<0,1,0><<<MQ/4, 256, 0, stream>>>(query, qn_g, qn_b, nullptr, nullptr, qn, MQ);
  // 3. v = featn @ W_v^T + b_v  (bf16)
  mgemm_k<0,1,0><<<dim3(3, MV/128), 256, 0, stream>>>(featn, wv, b_v, nullptr, vbuf,
                                                      MV, DIMD, DIMD, DIMD);
  // 4. offsets|logits = qn @ Wcat^T + bcat  (fp32, ldc 216, Npad 256)
  mgemm_k<0,0,0><<<dim3(2, MQ/128), 256, 0, stream>>>(qn, wcat, bcat, nullptr, offaw,
                                                      MQ, DIMD, 216, 216);
  // 4.5 point prep: softmax + bilinear weights + gather offsets (1 thread per (bq,h))
  msda_prep_k<<<(MQ*HEADS + 255)/256, 256, 0, stream>>>(offaw, refp, sshp, lst, pairs);
  // 5. gather -> msda bf16
  msda_gather_k<<<MQ*HEADS/8, 256, 0, stream>>>(vbuf, pairs, msda);
  // 6. x1 = qn + msda @ W_o^T + b_o  (bf16)
  mgemm_k<0,1,1><<<dim3(3, MQ/128), 256, 0, stream>>>(msda, wo, b_o, qn, x1,
                                                      MQ, DIMD, DIMD, DIMD);
  // 7. x2 = LN(x1) bf16
  ln_k<1,1,0><<<MQ/4, 256, 0, stream>>>(x1, n1_g, n1_b, nullptr, nullptr, x2, MQ);
  // 8. h = gelu(x2 @ W1^T + b1)  (bf16)
  mgemm_k<1,1,0><<<dim3(8, MQ/128), 256, 0, stream>>>(x2, w1, b1, nullptr, hbuf,
                                                      MQ, DIMD, FFN, FFN);
  // 9. y = x2 + h @ W2^T + b2  (bf16)
  mgemm_k<0,1,1><<<dim3(3, MQ/128), 256, 0, stream>>>(hbuf, w2, b2, x2, ybuf,
                                                      MQ, FFN, DIMD, DIMD);
  // 10. out = query + gamma * LN(y)
  ln_k<1,0,1><<<MQ/4, 256, 0, stream>>>(ybuf, n2_g, n2_b, query, gam, (float*)d_out, MQ);
}

// Round 4
// 305.742 us; speedup vs baseline: 3.6986x; 1.0224x over previous
//
#include <hip/hip_runtime.h>
#include <hip/hip_bf16.h>

// ---------------- problem constants ----------------
#define DIMD 384
#define HEADS 6
#define DH 64
#define LEVELS 3
#define POINTS 4
#define FFN 1024
#define BB 4
#define NQ 4096
#define NV 21504
#define MQ (BB*NQ)   // 16384
#define MV (BB*NV)   // 86016
#define EPSF 1e-6f

typedef __hip_bfloat16 bf16;
typedef __attribute__((ext_vector_type(8))) short bf16x8;
typedef __attribute__((ext_vector_type(4))) float f32x4;

__device__ __forceinline__ float wave_sum(float v){
  #pragma unroll
  for(int o=32;o;o>>=1) v += __shfl_xor(v,o);
  return v;
}

// ---------------- weight prep: fp32 -> bf16 (+ concat/pad W_off|W_aw to 256 rows) ----------------
__global__ __launch_bounds__(256) void prep_k(
  const float* __restrict__ Wv, const float* __restrict__ Wo,
  const float* __restrict__ W1, const float* __restrict__ W2,
  const float* __restrict__ Woff, const float* __restrict__ Waw,
  const float* __restrict__ boff, const float* __restrict__ baw,
  bf16* __restrict__ wv, bf16* __restrict__ wo, bf16* __restrict__ w1,
  bf16* __restrict__ w2, bf16* __restrict__ wcat, float* __restrict__ bcat)
{
  int i = blockIdx.x*256 + threadIdx.x;
  if(i < 147456){ wv[i] = __float2bfloat16(Wv[i]); return; }
  i -= 147456;
  if(i < 147456){ wo[i] = __float2bfloat16(Wo[i]); return; }
  i -= 147456;
  if(i < 393216){ w1[i] = __float2bfloat16(W1[i]); return; }
  i -= 393216;
  if(i < 393216){ w2[i] = __float2bfloat16(W2[i]); return; }
  i -= 393216;
  if(i < 98304){
    int r = i/384, c = i - r*384;
    float v = r<144 ? Woff[r*384+c] : (r<216 ? Waw[(r-144)*384+c] : 0.f);
    wcat[i] = __float2bfloat16(v); return;
  }
  i -= 98304;
  if(i < 256){ bcat[i] = i<144 ? boff[i] : (i<216 ? baw[i-144] : 0.f); }
}

// ---------------- row LayerNorm (DIMD=384), templated in/out dtype ----------------
template<int INBF,int OUTBF,int FINAL>
__global__ __launch_bounds__(256) void ln_k(const void* __restrict__ xv,
    const float* __restrict__ g, const float* __restrict__ b,
    const float* __restrict__ q, const float* __restrict__ gamma,
    void* __restrict__ outv, int nrows)
{
  int row = blockIdx.x*4 + (threadIdx.x>>6);
  int lane = threadIdx.x & 63;
  if(row >= nrows) return;
  float vals[6];
  float s=0.f, s2=0.f;
  #pragma unroll
  for(int i=0;i<6;i++){
    float v;
    if constexpr(INBF) v = __bfloat162float(((const bf16*)xv)[(size_t)row*DIMD + lane + i*64]);
    else               v = ((const float*)xv)[(size_t)row*DIMD + lane + i*64];
    vals[i]=v; s += v; s2 += v*v;
  }
  s = wave_sum(s); s2 = wave_sum(s2);
  float m = s*(1.f/DIMD);
  float var = s2*(1.f/DIMD) - m*m;
  float r = rsqrtf(var + EPSF);
  #pragma unroll
  for(int i=0;i<6;i++){
    int k = lane + i*64;
    float t = (vals[i]-m)*r*g[k] + b[k];
    if constexpr(FINAL){
      t = q[(size_t)row*DIMD + k] + gamma[k]*t;
      ((float*)outv)[(size_t)row*DIMD + k] = t;
    } else if constexpr(OUTBF){
      ((bf16*)outv)[(size_t)row*DIMD + k] = __float2bfloat16(t);
    } else {
      ((float*)outv)[(size_t)row*DIMD + k] = t;
    }
  }
}

// ---------------- fused LN + value projection ----------------
// v[128 rows][384] = LN(feat rows) @ W_v^T + b_v, single pass over N.
// 512 threads = 8 waves (2 M x 4 N). A resident in LDS (padded 392), B reg-staged
// into padded Bs[384][72] per BK=64 chunk.
#define ALD 392
#define BLD 72
__global__ __launch_bounds__(512) void vproj_k(
    const float* __restrict__ feat, const float* __restrict__ fg,
    const float* __restrict__ fb, const bf16* __restrict__ wv,
    const float* __restrict__ bias, bf16* __restrict__ out)
{
  extern __shared__ char smem[];
  short* As = (short*)smem;                      // [128][392]
  short* Bs = (short*)(smem + 128*ALD*2);        // [384][72]
  const int tid = threadIdx.x;
  const int wid = tid>>6, lane = tid&63;
  const int m0 = blockIdx.x*128;

  // ---- phase 1: LN(feat) rows -> As (bf16) ----
  {
    const int li = lane & 15;          // 0..15 within-row lane
    #pragma unroll
    for(int it=0; it<4; it++){
      const int r = wid*16 + it*4 + (lane>>4);   // tile row 0..127
      const float* fr = feat + (size_t)(m0+r)*DIMD;
      float4 v[6];
      float s=0.f, s2=0.f;
      #pragma unroll
      for(int j=0;j<6;j++){
        v[j] = *(const float4*)(fr + li*4 + j*64);
        s  += v[j].x + v[j].y + v[j].z + v[j].w;
        s2 += v[j].x*v[j].x + v[j].y*v[j].y + v[j].z*v[j].z + v[j].w*v[j].w;
      }
      #pragma unroll
      for(int o=1;o<16;o<<=1){ s += __shfl_xor(s,o); s2 += __shfl_xor(s2,o); }
      const float m  = s*(1.f/DIMD);
      const float rs = rsqrtf(s2*(1.f/DIMD) - m*m + EPSF);
      #pragma unroll
      for(int j=0;j<6;j++){
        const int col = li*4 + j*64;
        const float4 g4 = *(const float4*)(fg + col);
        const float4 b4 = *(const float4*)(fb + col);
        short4 o4;
        o4.x = __builtin_bit_cast(short, __float2bfloat16((v[j].x-m)*rs*g4.x + b4.x));
        o4.y = __builtin_bit_cast(short, __float2bfloat16((v[j].y-m)*rs*g4.y + b4.y));
        o4.z = __builtin_bit_cast(short, __float2bfloat16((v[j].z-m)*rs*g4.z + b4.z));
        o4.w = __builtin_bit_cast(short, __float2bfloat16((v[j].w-m)*rs*g4.w + b4.w));
        *(short4*)(As + r*ALD + col) = o4;
      }
    }
  }

  // ---- phase 2: K-loop, B reg-staged, MFMA ----
  const int wr = wid>>2, wc = wid&3;           // 2 x 4 wave grid
  f32x4 acc[4][6] = {};
  for(int k0=0; k0<DIMD; k0+=64){
    // stage Bs[384][72] chunk (cols k0..k0+63) via regs (padded ds_write)
    #pragma unroll
    for(int u=0;u<6;u++){
      const int t = wid*6 + u;                 // 0..47
      const int n = t*8 + (lane>>3);           // 0..383 weight row
      const int kc = (lane&7)*8;
      bf16x8 w8 = *(const bf16x8*)(wv + (size_t)n*DIMD + k0 + kc);
      *(bf16x8*)(Bs + n*BLD + kc) = w8;
    }
    __syncthreads();
    #pragma unroll
    for(int ks=0;ks<2;ks++){
      bf16x8 af[4], bfr[6];
      #pragma unroll
      for(int i=0;i<4;i++){
        const int ar = wr*64 + i*16 + (lane&15);
        af[i] = *(const bf16x8*)(As + ar*ALD + k0 + ks*32 + (lane>>4)*8);
      }
      #pragma unroll
      for(int j=0;j<6;j++){
        const int br = wc*96 + j*16 + (lane&15);
        bfr[j] = *(const bf16x8*)(Bs + br*BLD + ks*32 + (lane>>4)*8);
      }
      #pragma unroll
      for(int i=0;i<4;i++)
        #pragma unroll
        for(int j=0;j<6;j++)
          acc[i][j] = __builtin_amdgcn_mfma_f32_16x16x32_bf16(af[i], bfr[j], acc[i][j], 0,0,0);
    }
    __syncthreads();
  }
  // ---- epilogue ----
  #pragma unroll
  for(int i=0;i<4;i++){
    const int rbase = m0 + wr*64 + i*16 + (lane>>4)*4;
    #pragma unroll
    for(int j=0;j<6;j++){
      const int col = wc*96 + j*16 + (lane&15);
      const float bv = bias[col];
      #pragma unroll
      for(int rr=0;rr<4;rr++){
        out[(size_t)(rbase+rr)*DIMD + col] = __float2bfloat16(acc[i][j][rr] + bv);
      }
    }
  }
}

// ---------------- bf16 MFMA GEMM: C = epi(A @ W^T + bias [+ res]) ----------------
template<int GELU_,int STBF,int RES>
__global__ __launch_bounds__(256) void mgemm_k(
    const bf16* __restrict__ A, const bf16* __restrict__ Bw,
    const float* __restrict__ bias, const bf16* __restrict__ res,
    void* __restrict__ Cv, int M, int K, int Nreal, int ldc)
{
  __shared__ __align__(16) short As[128*64];
  __shared__ __align__(16) short Bs[128*64];
  const int tid  = threadIdx.x;
  const int wid  = tid>>6, lane = tid&63;
  const int wr   = wid>>1, wc = wid&1;
  const int m0   = blockIdx.y*128, n0 = blockIdx.x*128;
  f32x4 acc[4][4] = {};

  const int sr = (lane>>3);
  const int sc = (lane&7)*8;

  for(int k0=0; k0<K; k0+=64){
    #pragma unroll
    for(int u=0;u<4;u++){
      const int t = wid*4 + u;
      const int r = t*8 + sr;
      const bf16* srcA = A  + (size_t)(m0+r)*K + k0 + sc;
      const bf16* srcB = Bw + (size_t)(n0+r)*K + k0 + sc;
      __builtin_amdgcn_global_load_lds((const __attribute__((address_space(1))) void*)srcA,
          (__attribute__((address_space(3))) void*)(As + t*512), 16, 0, 0);
      __builtin_amdgcn_global_load_lds((const __attribute__((address_space(1))) void*)srcB,
          (__attribute__((address_space(3))) void*)(Bs + t*512), 16, 0, 0);
    }
    asm volatile("s_waitcnt vmcnt(0)" ::: "memory");
    __syncthreads();
    #pragma unroll
    for(int ks=0;ks<2;ks++){
      bf16x8 af[4], bfr[4];
      #pragma unroll
      for(int i=0;i<4;i++){
        const int ar = wr*64 + i*16 + (lane&15);
        af[i]  = *(const bf16x8*)(As + ar*64 + ks*32 + (lane>>4)*8);
        const int br = wc*64 + i*16 + (lane&15);
        bfr[i] = *(const bf16x8*)(Bs + br*64 + ks*32 + (lane>>4)*8);
      }
      #pragma unroll
      for(int i=0;i<4;i++)
        #pragma unroll
        for(int j=0;j<4;j++)
          acc[i][j] = __builtin_amdgcn_mfma_f32_16x16x32_bf16(af[i], bfr[j], acc[i][j], 0,0,0);
    }
    __syncthreads();
  }
  #pragma unroll
  for(int i=0;i<4;i++){
    const int rbase = m0 + wr*64 + i*16 + (lane>>4)*4;
    #pragma unroll
    for(int j=0;j<4;j++){
      const int col = n0 + wc*64 + j*16 + (lane&15);
      if(col >= Nreal) continue;
      const float bv = bias[col];
      #pragma unroll
      for(int rr=0;rr<4;rr++){
        const int rowg = rbase + rr;
        float v = acc[i][j][rr] + bv;
        if constexpr(RES) v += __bfloat162float(res[(size_t)rowg*ldc + col]);
        if constexpr(GELU_){ float u=v; v = 0.5f*u*(1.f+tanhf(0.7978845608028654f*(u+0.044715f*u*u*u))); }
        if constexpr(STBF) ((bf16*)Cv)[(size_t)rowg*ldc + col] = __float2bfloat16(v);
        else               ((float*)Cv)[(size_t)rowg*ldc + col] = v;
      }
    }
  }
}

// ---------------- MSDA point prep: one THREAD per (bq, head) ----------------
__global__ __launch_bounds__(256) void msda_prep_k(
    const float* __restrict__ offaw, const float* __restrict__ refp,
    const int* __restrict__ sshapes, const int* __restrict__ lstart,
    uint2* __restrict__ pairs)
{
  const int t = blockIdx.x*256 + threadIdx.x;
  if(t >= MQ*HEADS) return;
  const int bq = t/6, h = t - bq*6;
  const int b  = bq >> 12;
  const float* row = offaw + (size_t)bq*216;
  float awv[12];
  float mx = -1e30f;
  #pragma unroll
  for(int i=0;i<12;i++){ awv[i] = row[144 + h*12 + i]; mx = fmaxf(mx, awv[i]); }
  float ssum = 0.f;
  #pragma unroll
  for(int i=0;i<12;i++){ awv[i] = __expf(awv[i]-mx); ssum += awv[i]; }
  const float inv = 1.f/ssum;
  uint2* pw = pairs + (size_t)t*48;
  int c48 = 0;
  #pragma unroll
  for(int l=0;l<LEVELS;l++){
    const int hh = sshapes[2*l], ww = sshapes[2*l+1];
    const int st = lstart[l];
    const float rx = refp[((size_t)bq*LEVELS + l)*2 + 0];
    const float ry = refp[((size_t)bq*LEVELS + l)*2 + 1];
    #pragma unroll
    for(int p=0;p<POINTS;p++){
      const float ox = row[((h*LEVELS + l)*POINTS + p)*2 + 0];
      const float oy = row[((h*LEVELS + l)*POINTS + p)*2 + 1];
      const float px = (rx + ox/(float)ww)*(float)ww - 0.5f;
      const float py = (ry + oy/(float)hh)*(float)hh - 0.5f;
      const float fx0 = floorf(px), fy0 = floorf(py);
      const int x0 = (int)fx0, y0 = (int)fy0;
      const float wx1 = px - fx0, wx0 = 1.f - wx1;
      const float wy1 = py - fy0, wy0 = 1.f - wy1;
      const float aww = awv[l*POINTS+p]*inv;
      #pragma unroll
      for(int c=0;c<4;c++){
        const int xi = x0 + (c&1);
        const int yi = y0 + (c>>1);
        const float wgt = (c&1 ? wx1 : wx0) * (c>>1 ? wy1 : wy0);
        const bool valid = (xi>=0) & (xi<=ww-1) & (yi>=0) & (yi<=hh-1);
        const int cx = min(max(xi,0), ww-1);
        const int cy = min(max(yi,0), hh-1);
        const unsigned off = (unsigned)((((b*NV + st + cy*ww + cx)*DIMD) + h*DH)*2);
        const float w = valid ? wgt*aww : 0.f;
        uint2 pr; pr.x = off; pr.y = __float_as_uint(w);
        pw[c48++] = pr;
      }
    }
  }
}

// ---------------- MSDA gather: half-wave (32 lanes) per (bq,h), 2 ch/lane ----------------
__global__ __launch_bounds__(256) void msda_gather_k(
    const bf16* __restrict__ v, const uint2* __restrict__ pairs,
    bf16* __restrict__ out)
{
  const int wid  = blockIdx.x*4 + (threadIdx.x>>6);
  const int lane = threadIdx.x & 63;
  const int pid  = wid*2 + (lane>>5);
  const int ch   = lane & 31;
  const uint2* pw = pairs + (size_t)pid*48;
  const char* vb = (const char*)v;
  float a0 = 0.f, a1 = 0.f;
  #pragma unroll
  for(int c=0;c<48;c++){
    const uint2 pr = pw[c];
    const unsigned g = *(const unsigned*)(vb + pr.x + (ch<<2));
    const float w = __uint_as_float(pr.y);
    const float lo = __uint_as_float(g << 16);
    const float hi = __uint_as_float(g & 0xffff0000u);
    a0 = fmaf(w, lo, a0);
    a1 = fmaf(w, hi, a1);
  }
  const int bq = pid/6, h = pid - bq*6;
  const unsigned u0 = (unsigned)__builtin_bit_cast(unsigned short, __float2bfloat16(a0));
  const unsigned u1 = (unsigned)__builtin_bit_cast(unsigned short, __float2bfloat16(a1));
  *(unsigned*)((char*)out + (size_t)bq*768 + h*128 + (ch<<2)) = u0 | (u1<<16);
}

// ---------------- launcher ----------------
static inline size_t rnd(size_t x){ return (x + 511) & ~(size_t)511; }

extern "C" void kernel_launch(void* const* d_in, const int* in_sizes, int n_in,
                              void* d_out, int out_size, void* d_ws, size_t ws_size,
                              hipStream_t stream)
{
  const float* query = (const float*)d_in[0];
  const float* refp  = (const float*)d_in[1];
  const float* feat  = (const float*)d_in[2];
  const int*   sshp  = (const int*)d_in[3];
  const int*   lst   = (const int*)d_in[4];
  const float* qn_g  = (const float*)d_in[5];
  const float* qn_b  = (const float*)d_in[6];
  const float* fn_g  = (const float*)d_in[7];
  const float* fn_b  = (const float*)d_in[8];
  const float* W_off = (const float*)d_in[9];
  const float* b_off = (const float*)d_in[10];
  const float* W_aw  = (const float*)d_in[11];
  const float* b_aw  = (const float*)d_in[12];
  const float* W_v   = (const float*)d_in[13];
  const float* b_v   = (const float*)d_in[14];
  const float* W_o   = (const float*)d_in[15];
  const float* b_o   = (const float*)d_in[16];
  const float* n1_g  = (const float*)d_in[17];
  const float* n1_b  = (const float*)d_in[18];
  const float* W1    = (const float*)d_in[19];
  const float* b1    = (const float*)d_in[20];
  const float* W2    = (const float*)d_in[21];
  const float* b2    = (const float*)d_in[22];
  const float* n2_g  = (const float*)d_in[23];
  const float* n2_b  = (const float*)d_in[24];
  const float* gam   = (const float*)d_in[25];

  // ---- workspace layout (~160 MB) ----
  char* p = (char*)d_ws;
  bf16* vbuf  = (bf16*)p;  p += rnd((size_t)MV*DIMD*2);
  bf16* qn    = (bf16*)p;  p += rnd((size_t)MQ*DIMD*2);
  bf16* wv    = (bf16*)p;  p += rnd((size_t)147456*2);
  bf16* wo    = (bf16*)p;  p += rnd((size_t)147456*2);
  bf16* w1    = (bf16*)p;  p += rnd((size_t)393216*2);
  bf16* w2    = (bf16*)p;  p += rnd((size_t)393216*2);
  bf16* wcat  = (bf16*)p;  p += rnd((size_t)98304*2);
  float* bcat = (float*)p; p += rnd((size_t)256*4);
  bf16* hbuf  = (bf16*)p;  p += rnd((size_t)MQ*FFN*2);
  bf16* ybuf  = (bf16*)p;  p += rnd((size_t)MQ*DIMD*2);
  float* offaw = (float*)p; p += rnd((size_t)MQ*216*4);
  bf16*  msda  = (bf16*)p;  p += rnd((size_t)MQ*DIMD*2);
  bf16*  x1    = (bf16*)p;  p += rnd((size_t)MQ*DIMD*2);
  bf16*  x2    = (bf16*)p;  p += rnd((size_t)MQ*DIMD*2);
  // pairs table (37.7 MB) aliases hbuf+ybuf (both dead until FFN steps)
  uint2* pairs = (uint2*)hbuf;

  // raise dynamic-LDS cap for vproj_k (host-side attribute; capture-safe)
  const int VPROJ_LDS = (128*ALD + 384*BLD)*2;   // 155,648 B
  static_assert((128*ALD + 384*BLD)*2 <= 160*1024, "LDS over budget");
  hipFuncSetAttribute((const void*)vproj_k,
                      hipFuncAttributeMaxDynamicSharedMemorySize, VPROJ_LDS);

  // 1. weights -> bf16 (+concat/pad)
  prep_k<<<4609, 256, 0, stream>>>(W_v, W_o, W1, W2, W_off, W_aw, b_off, b_aw,
                                   wv, wo, w1, w2, wcat, bcat);
  // 2. qn = LN(query) bf16
  ln_k<0,1,0><<<MQ/4, 256, 0, stream>>>(query, qn_g, qn_b, nullptr, nullptr, qn, MQ);
  // 3. v = LN(feat) @ W_v^T + b_v  (fused, single N pass, bf16 out)
  vproj_k<<<MV/128, 512, VPROJ_LDS, stream>>>(feat, fn_g, fn_b, wv, b_v, vbuf);
  // 4. offsets|logits = qn @ Wcat^T + bcat  (fp32, ldc 216, Npad 256)
  mgemm_k<0,0,0><<<dim3(2, MQ/128), 256, 0, stream>>>(qn, wcat, bcat, nullptr, offaw,
                                                      MQ, DIMD, 216, 216);
  // 4.5 point prep
  msda_prep_k<<<(MQ*HEADS + 255)/256, 256, 0, stream>>>(offaw, refp, sshp, lst, pairs);
  // 5. gather -> msda bf16
  msda_gather_k<<<MQ*HEADS/8, 256, 0, stream>>>(vbuf, pairs, msda);
  // 6. x1 = qn + msda @ W_o^T + b_o  (bf16)
  mgemm_k<0,1,1><<<dim3(3, MQ/128), 256, 0, stream>>>(msda, wo, b_o, qn, x1,
                                                      MQ, DIMD, DIMD, DIMD);
  // 7. x2 = LN(x1) bf16
  ln_k<1,1,0><<<MQ/4, 256, 0, stream>>>(x1, n1_g, n1_b, nullptr, nullptr, x2, MQ);
  // 8. h = gelu(x2 @ W1^T + b1)  (bf16)
  mgemm_k<1,1,0><<<dim3(8, MQ/128), 256, 0, stream>>>(x2, w1, b1, nullptr, hbuf,
                                                      MQ, DIMD, FFN, FFN);
  // 9. y = x2 + h @ W2^T + b2  (bf16)
  mgemm_k<0,1,1><<<dim3(3, MQ/128), 256, 0, stream>>>(hbuf, w2, b2, x2, ybuf,
                                                      MQ, FFN, DIMD, DIMD);
  // 10. out = query + gamma * LN(y)
  ln_k<1,0,1><<<MQ/4, 256, 0, stream>>>(ybuf, n2_g, n2_b, query, gam, (float*)d_out, MQ);
}